// Round 6
// baseline (1624.150 us; speedup 1.0000x reference)
//
#include <hip/hip_runtime.h>
#include <stdint.h>
#include <math.h>

typedef unsigned short u16;
typedef __attribute__((ext_vector_type(2))) float floatx2;
typedef __attribute__((ext_vector_type(4))) float floatx4;
typedef __attribute__((ext_vector_type(4))) unsigned int uintx4;
typedef __attribute__((ext_vector_type(8))) __bf16 bf16x8;

#define B_ROWS 4096
#define DK 512
#define NKEYS 65536
#define NCHUNK 32
#define CHUNK (NKEYS / NCHUNK)        // 2048
#define SLOTS 32
#define CAND_PER_ROW (NCHUNK * SLOTS) // 1024
#define THRESH 0.135f

// d_out layout (float32): out[4096*512], conf[1], top_idx[4096*8], attn[4096*8]
#define CONF_OFF 2097152
#define IDX_OFF  2097153
#define ATTN_OFF (IDX_OFF + B_ROWS * 8)

__device__ __forceinline__ u16 f2bf(float x) {
    union { float f; unsigned int u; } v; v.f = x;
    unsigned int r = v.u + 0x7fffu + ((v.u >> 16) & 1u);
    return (u16)(r >> 16);
}

// async global->LDS, 16B per lane; LDS dest is wave-uniform base + lane*16
__device__ __forceinline__ void gload_lds16(const u16* g, u16* l) {
    __builtin_amdgcn_global_load_lds(
        (const __attribute__((address_space(1))) unsigned int*)g,
        (__attribute__((address_space(3))) unsigned int*)l,
        16, 0, 0);
}

// numpy pairwise_sum emulation for sum of squares, n=128 base block:
// r[j] = a[j]^2, then r[j] += a[i+j]^2 for i=8..120, combine as
// ((r0+r1)+(r2+r3))+((r4+r5)+(r6+r7)). Strict f32, no contraction.
__device__ __forceinline__ float np_block128_sq(const float* a) {
#pragma clang fp contract(off)
    float r[8];
    floatx4 p0 = *(const floatx4*)&a[0];
    floatx4 p1 = *(const floatx4*)&a[4];
    r[0] = p0.x * p0.x; r[1] = p0.y * p0.y; r[2] = p0.z * p0.z; r[3] = p0.w * p0.w;
    r[4] = p1.x * p1.x; r[5] = p1.y * p1.y; r[6] = p1.z * p1.z; r[7] = p1.w * p1.w;
    for (int i = 8; i < 128; i += 8) {
        floatx4 q0 = *(const floatx4*)&a[i];
        floatx4 q1 = *(const floatx4*)&a[i + 4];
        r[0] += q0.x * q0.x; r[1] += q0.y * q0.y;
        r[2] += q0.z * q0.z; r[3] += q0.w * q0.w;
        r[4] += q1.x * q1.x; r[5] += q1.y * q1.y;
        r[6] += q1.z * q1.z; r[7] += q1.w * q1.w;
    }
    return ((r[0] + r[1]) + (r[2] + r[3])) + ((r[4] + r[5]) + (r[6] + r[7]));
}

// n=512: numpy recursion: (B0+B1)+(B2+B3)
__device__ __forceinline__ float np_sum512_sq(const float* a) {
#pragma clang fp contract(off)
    float b0 = np_block128_sq(a);
    float b1 = np_block128_sq(a + 128);
    float b2 = np_block128_sq(a + 256);
    float b3 = np_block128_sq(a + 384);
    return (b0 + b1) + (b2 + b3);
}

// correctly-rounded f32 sqrt via f64 (2p+2 rule), immune to compile flags
__device__ __forceinline__ float sqrt_f32_cr(float s) {
    return (float)sqrt((double)s);
}
// correctly-rounded f32 divide via f64 (double-rounding prob ~2^-29)
__device__ __forceinline__ float div_f32_cr(float a, float b) {
    return (float)((double)a / (double)b);
}

// ---------------- P0: W transpose (WT[i][j] = W[j][i]) ----------------
__global__ __launch_bounds__(256) void transpose_w(const float* __restrict__ w,
                                                   float* __restrict__ wt) {
    int j = blockIdx.x, t = threadIdx.x;
    float a = w[(size_t)j * DK + t];
    float b = w[(size_t)j * DK + t + 256];
    wt[(size_t)t * DK + j] = a;
    wt[(size_t)(t + 256) * DK + j] = b;
}

// ---------------- C: emulated-np f32 key normalize ----------------
// one thread per key row; writes keys_n f32 IN PLACE over mem_keys
// (harness restores d_in from pristine before every launch) + bf16 copy.
__global__ __launch_bounds__(256) void prep_keys(float* __restrict__ mk,
                                                 u16* __restrict__ kbf) {
    const int row = blockIdx.x * 256 + threadIdx.x;
    float* kp = mk + (size_t)row * DK;
    float s = np_sum512_sq(kp);
    float nrm = sqrt_f32_cr(s) + 1e-8f;   // norm + eps, both f32 rounded
    for (int i = 0; i < DK; i += 8) {
        floatx4 p0 = *(const floatx4*)&kp[i];
        floatx4 p1 = *(const floatx4*)&kp[i + 4];
        floatx4 n0, n1;
        n0.x = div_f32_cr(p0.x, nrm); n0.y = div_f32_cr(p0.y, nrm);
        n0.z = div_f32_cr(p0.z, nrm); n0.w = div_f32_cr(p0.w, nrm);
        n1.x = div_f32_cr(p1.x, nrm); n1.y = div_f32_cr(p1.y, nrm);
        n1.z = div_f32_cr(p1.z, nrm); n1.w = div_f32_cr(p1.w, nrm);
        union { uintx4 v; u16 u[8]; } pk;
        pk.u[0] = f2bf(n0.x); pk.u[1] = f2bf(n0.y);
        pk.u[2] = f2bf(n0.z); pk.u[3] = f2bf(n0.w);
        pk.u[4] = f2bf(n1.x); pk.u[5] = f2bf(n1.y);
        pk.u[6] = f2bf(n1.z); pk.u[7] = f2bf(n1.w);
        *(floatx4*)&kp[i] = n0;
        *(floatx4*)&kp[i + 4] = n1;
        *(uintx4*)&kbf[(size_t)row * DK + i] = pk.v;
    }
}

// ---------------- AB: emulated-np f32 enc + fused q normalize ----------------
// Unconditional fmaf chain (fmaf(0,w,a)==a bit-exactly since spike values
// are exactly 0.0/1.0 and the accumulator can never be -0), batched 16-deep
// loads so L2 latency pipelines instead of serializing per-iteration, and
// thread->column remap {t,t+256} -> {2t,2t+1} so each row contributes one
// float2 load instead of two scalar loads.
__global__ __launch_bounds__(256) void fuse_q(const float* __restrict__ q,
                                              const float* __restrict__ spike,
                                              const float* __restrict__ wt,
                                              const float* __restrict__ bvec,
                                              float* __restrict__ qn2f,
                                              u16* __restrict__ qbf) {
    __shared__ __align__(16) float s_sp[DK];
    __shared__ __align__(16) float s_q[DK];
    __shared__ __align__(16) float s_y[DK];
    __shared__ float s_nq;
    __shared__ float s_ny;
    const int t = threadIdx.x, b = blockIdx.x;
    s_sp[t] = spike[(size_t)b * DK + t];
    s_sp[t + 256] = spike[(size_t)b * DK + t + 256];
    s_q[t] = q[(size_t)b * DK + t];
    s_q[t + 256] = q[(size_t)b * DK + t + 256];
    __syncthreads();

    const int c0 = 2 * t;   // this thread owns columns c0 and c0+1
    float a0 = 0.f, a1 = 0.f;
    for (int i = 0; i < DK; i += 16) {
        float sv[16]; floatx2 wv[16];
#pragma unroll
        for (int u = 0; u < 16; ++u) {
            sv[u] = s_sp[i + u];
            wv[u] = *(const floatx2*)&wt[(size_t)(i + u) * DK + c0];
        }
#pragma unroll
        for (int u = 0; u < 16; ++u) {
            a0 = fmaf(sv[u], wv[u].x, a0);   // sv==0 contributes exactly nothing
            a1 = fmaf(sv[u], wv[u].y, a1);
        }
    }

    if (t == 0) s_nq = sqrt_f32_cr(np_sum512_sq(s_q)) + 1e-8f;
    __syncthreads();
    float nq = s_nq;
    float qn0 = div_f32_cr(s_q[c0], nq);
    float qn1 = div_f32_cr(s_q[c0 + 1], nq);
    float e0 = a0 + bvec[c0];             // matmul result + b, f32 add
    float e1 = a1 + bvec[c0 + 1];
    float y0, y1;
    {
#pragma clang fp contract(off)
        float u0 = 0.7f * qn0; float v0 = 0.3f * e0; y0 = u0 + v0;
        float u1 = 0.7f * qn1; float v1 = 0.3f * e1; y1 = u1 + v1;
    }
    s_y[c0] = y0; s_y[c0 + 1] = y1;
    __syncthreads();
    if (t == 0) s_ny = sqrt_f32_cr(np_sum512_sq(s_y)) + 1e-8f;
    __syncthreads();
    float ny = s_ny;
    float f0 = div_f32_cr(y0, ny);
    float f1 = div_f32_cr(y1, ny);
    *(floatx2*)&qn2f[(size_t)b * DK + c0] = (floatx2){f0, f1};
    union { unsigned int u; u16 h[2]; } pk;
    pk.h[0] = f2bf(f0); pk.h[1] = f2bf(f1);
    *(unsigned int*)&qbf[(size_t)b * DK + c0] = pk.u;
}

// ---------------- D: bf16 MFMA GEMM + threshold candidate filter ----------------
// Round-4 grid restored (x=qtile, y=chunk; XCD swizzle reverted — it raised
// FETCH 1.2->1.47 GB). New: (a) A fragments read straight from global into
// registers (L2-hot; kills ldsA + 16 KB/K-step of LDS write traffic),
// (b) double-buffered B with prefetch-issued-BEFORE-compute (T3-minimum
// 2-phase): the barrier's vmcnt(0) drain lands after ~32 MFMA of cover.
// A-loads are issued before the B prefetch so the compiler's A-wait
// (oldest in vmem queue) leaves the B prefetch (newest) outstanding.
// B keeps the XOR swizzle (inverse-swz global source + swz ds_read,
// linear LDS dest). Values bit-identical to the padded-LDS version.
__global__ __launch_bounds__(256, 4) void cand_gemm(const u16* __restrict__ qbf,
                                                    const u16* __restrict__ kbf,
                                                    int* __restrict__ cidx,
                                                    int* __restrict__ gcnt) {
    __shared__ u16 ldsB[2][128 * 64];
    const int t = threadIdx.x;
    const int lane = t & 63;
    const int wave = t >> 6;
    const int qbase = blockIdx.x * 128;
    const int chunk = blockIdx.y;
    const int r0 = 64 * (wave >> 1), c0 = 64 * (wave & 1);
    const int quad = lane >> 4, m16 = lane & 15;

    // B staging geometry: wave stages chunks m = wave*4+c (1 KB = 8 rows);
    // lane covers LDS row m*8+(lane>>3), col bytes (lane&7)*16; global col
    // inverse-swizzled: 16*((lane&7) ^ (lane>>3)).
    const int srow = lane >> 3;
    const int scol = ((lane & 7) ^ srow) << 3;     // u16 col offset

    // per-lane A base: row qbase+r0+m16, col quad*8 (u16)
    const u16* aRow = qbf + (size_t)(qbase + r0 + m16) * DK + quad * 8;

    floatx4 acc[4][4];

    // prologue: stage step 0 into buf 0
    {
        const u16* bB = kbf + (size_t)(chunk * CHUNK + wave * 32 + srow) * DK + scol;
#pragma unroll
        for (int c = 0; c < 4; ++c)
            gload_lds16(bB + (size_t)c * 8 * DK, &ldsB[0][(wave * 4 + c) * 512]);
    }
    __syncthreads();

    int cur = 0;
    for (int s = 0; s < 128; ++s) {          // s = iter*8 + kstep
        const int iter = s >> 3;
        const int ks = (s & 7) << 6;         // u16 col offset within row
        const int nbase = chunk * CHUNK + iter * 128;

        if ((s & 7) == 0) {
#pragma unroll
            for (int i = 0; i < 4; ++i)
#pragma unroll
                for (int j = 0; j < 4; ++j) acc[i][j] = (floatx4){0.f, 0.f, 0.f, 0.f};
        }

        // A fragments from global (issued FIRST — see header comment)
        bf16x8 afr[2][4];
#pragma unroll
        for (int h = 0; h < 2; ++h)
#pragma unroll
            for (int i = 0; i < 4; ++i)
                afr[h][i] = __builtin_bit_cast(bf16x8,
                    *(const uintx4*)(aRow + (size_t)i * 16 * DK + ks + h * 32));

        // B prefetch for step s+1 into the other buffer
        if (s < 127) {
            const int s2 = s + 1;
            const int nb2 = chunk * CHUNK + (s2 >> 3) * 128;
            const int ks2 = (s2 & 7) << 6;
            const u16* bB = kbf + (size_t)(nb2 + wave * 32 + srow) * DK + ks2 + scol;
#pragma unroll
            for (int c = 0; c < 4; ++c)
                gload_lds16(bB + (size_t)c * 8 * DK, &ldsB[cur ^ 1][(wave * 4 + c) * 512]);
        }

        // compute on buf[cur]
#pragma unroll
        for (int h = 0; h < 2; ++h) {
            const int cb = ((h * 4 + quad) ^ (m16 & 7)) << 4;   // swizzled byte col
            bf16x8 bfr[4];
#pragma unroll
            for (int j = 0; j < 4; ++j)
                bfr[j] = __builtin_bit_cast(bf16x8,
                    *(const uintx4*)((const char*)&ldsB[cur][0] + (c0 + 16 * j + m16) * 128 + cb));
#pragma unroll
            for (int i = 0; i < 4; ++i)
#pragma unroll
                for (int j = 0; j < 4; ++j)
                    acc[i][j] = __builtin_amdgcn_mfma_f32_16x16x32_bf16(
                        afr[h][i], bfr[j], acc[i][j], 0, 0, 0);
        }

        if ((s & 7) == 7) {
            // C layout: col=lane&15, row=quad*4+reg  [m89/m91-verified]
#pragma unroll
            for (int i = 0; i < 4; ++i)
#pragma unroll
                for (int j = 0; j < 4; ++j) {
                    int col = nbase + c0 + 16 * j + m16;
#pragma unroll
                    for (int r = 0; r < 4; ++r) {
                        float v = acc[i][j][r];
                        if (v > THRESH) {
                            int grow = qbase + r0 + 16 * i + quad * 4 + r;
                            int slot = atomicAdd(&gcnt[grow * NCHUNK + chunk], 1);
                            if (slot < SLOTS)
                                cidx[(size_t)grow * CAND_PER_ROW + chunk * SLOTS + slot] = col;
                        }
                    }
                }
        }
        __syncthreads();
        cur ^= 1;
    }
}

// ---------------- E: dense rescore (np-f32 emulation) + exact top-8 ----------------
__global__ __launch_bounds__(256) void finalize_rows(const int* __restrict__ cidx,
                                                     const int* __restrict__ gcnt,
                                                     const float* __restrict__ qn2f,
                                                     const float* __restrict__ keys_n,
                                                     const float* __restrict__ mem_values,
                                                     float* __restrict__ out,
                                                     double* __restrict__ confp) {
    __shared__ __align__(16) float s_q[DK];
    __shared__ int s_cnt[NCHUNK];
    __shared__ int s_kin[CAND_PER_ROW];
    __shared__ float s_dv[CAND_PER_ROW];
    __shared__ int s_di[CAND_PER_ROW];
    __shared__ int s_n;
    __shared__ float s_lv[64][8];
    __shared__ int s_li[64][8];
    __shared__ float s_tv[8];
    __shared__ int s_ti[8];
    __shared__ double s_attn[8];

    const int b = blockIdx.x, t = threadIdx.x, lane = t & 63, wave = t >> 6;
    s_q[t] = qn2f[(size_t)b * DK + t];
    s_q[t + 256] = qn2f[(size_t)b * DK + t + 256];
    if (t == 0) s_n = 0;
    if (t < NCHUNK) {
        int c = gcnt[b * NCHUNK + t];
        s_cnt[t] = c < SLOTS ? c : SLOTS;
    }
    __syncthreads();

    // dense compaction of active candidate key-indices
    for (int s = t; s < CAND_PER_ROW; s += 256) {
        int ch = s >> 5, sl = s & 31;
        if (sl < s_cnt[ch]) {
            int pos = atomicAdd(&s_n, 1);
            s_kin[pos] = cidx[(size_t)b * CAND_PER_ROW + s];
        }
    }
    __syncthreads();
    const int n = s_n;

    // rescore: sequential-k single-accumulator fmaf chain over precomputed
    // keys_n (bit-identical to np f32 emulation verified in round 3)
    for (int p = t; p < n; p += 256) {
        int ki = s_kin[p];
        const float* kp = keys_n + (size_t)ki * DK;
        float acc = 0.f;
        for (int i = 0; i < DK; i += 4) {
            floatx4 kv = *(const floatx4*)&kp[i];
            acc = fmaf(s_q[i + 0], kv.x, acc);
            acc = fmaf(s_q[i + 1], kv.y, acc);
            acc = fmaf(s_q[i + 2], kv.z, acc);
            acc = fmaf(s_q[i + 3], kv.w, acc);
        }
        s_dv[p] = acc;
        s_di[p] = ki;
    }
    __syncthreads();

    // stage 1: each lane of wave 0 insertion-sorts its strided entries into
    // top-8 (desc by value; tie -> smaller key index = stable argsort)
    if (wave == 0) {
        float lv[8]; int li[8];
#pragma unroll
        for (int k = 0; k < 8; ++k) { lv[k] = -1e30f; li[k] = 0x7fffffff; }
        for (int p = lane; p < n; p += 64) {
            float v = s_dv[p];
            int ki = s_di[p];
            if (v > lv[7] || (v == lv[7] && ki < li[7])) {
                lv[7] = v; li[7] = ki;
#pragma unroll
                for (int k = 7; k > 0; --k) {
                    bool sw = (lv[k] > lv[k - 1]) ||
                              (lv[k] == lv[k - 1] && li[k] < li[k - 1]);
                    if (sw) {
                        float tv = lv[k]; lv[k] = lv[k - 1]; lv[k - 1] = tv;
                        int ti = li[k]; li[k] = li[k - 1]; li[k - 1] = ti;
                    }
                }
            }
        }
#pragma unroll
        for (int k = 0; k < 8; ++k) { s_lv[lane][k] = lv[k]; s_li[lane][k] = li[k]; }
    }
    __syncthreads();

    // stage 2: single-thread 64-way merge on sorted list heads (exact)
    if (t == 0) {
        int head[64];
#pragma unroll
        for (int l = 0; l < 64; ++l) head[l] = 0;
        for (int k = 0; k < 8; ++k) {
            float bv = -2e30f; int bi = 0x7fffffff; int bl = 0;
            for (int l = 0; l < 64; ++l) {
                int h = head[l];
                float v = s_lv[l][h];
                int ki = s_li[l][h];
                if (v > bv || (v == bv && ki < bi)) { bv = v; bi = ki; bl = l; }
            }
            head[bl]++;
            s_tv[k] = bv;
            s_ti[k] = (bi == 0x7fffffff) ? 0 : bi;
        }
        // softmax + entropy (f64 on the emulated-f32 top values)
        double mx = (double)s_tv[0];
        double e[8], sum = 0.0;
#pragma unroll
        for (int k = 0; k < 8; ++k) {
            e[k] = exp(((double)s_tv[k] - mx) / 0.1);
            sum += e[k];
        }
        double H = 0.0;
#pragma unroll
        for (int k = 0; k < 8; ++k) {
            double pa = e[k] / sum;
            s_attn[k] = pa;
            double pc = pa < 1e-8 ? 1e-8 : pa;
            H -= pc * log(pc);
        }
        confp[b] = 1.0 - H / (log(8.0) + 1e-8);
    }
    __syncthreads();

    if (t < 8) {
        out[IDX_OFF + (size_t)b * 8 + t] = (float)s_ti[t];
        out[ATTN_OFF + (size_t)b * 8 + t] = (float)s_attn[t];
    }
    for (int c = t; c < DK; c += 256) {
        double a = 0.0;
#pragma unroll
        for (int k = 0; k < 8; ++k)
            a += s_attn[k] * (double)mem_values[(size_t)s_ti[k] * DK + c];
        out[(size_t)b * DK + c] = (float)a;
    }
}

// ---------------- F: conf = mean over rows ----------------
__global__ __launch_bounds__(256) void conf_reduce(const double* __restrict__ confp,
                                                   float* __restrict__ out) {
    __shared__ double red[256];
    int t = threadIdx.x;
    double s = 0.0;
    for (int i = t; i < B_ROWS; i += 256) s += confp[i];
    red[t] = s;
    __syncthreads();
    for (int k = 128; k > 0; k >>= 1) {
        if (t < k) red[t] += red[t + k];
        __syncthreads();
    }
    if (t == 0) out[CONF_OFF] = (float)(red[0] / 4096.0);
}

extern "C" void kernel_launch(void* const* d_in, const int* in_sizes, int n_in,
                              void* d_out, int out_size, void* d_ws, size_t ws_size,
                              hipStream_t stream) {
    const float* q     = (const float*)d_in[0];
    const float* spike = (const float*)d_in[1];
    float*       mk    = (float*)d_in[2];   // normalized in place by prep_keys
    const float* mv    = (const float*)d_in[3];
    const float* w     = (const float*)d_in[4];
    const float* bvec  = (const float*)d_in[5];
    float* out = (float*)d_out;
    char* ws = (char*)d_ws;

    // workspace layout (~95 MB)
    u16*    qbf   = (u16*)   (ws);                       //  4 MB
    u16*    kbf   = (u16*)   (ws + (4ull  << 20));       // 64 MB
    float*  qn2f  = (float*) (ws + (68ull << 20));       //  8 MB
    int*    cidx  = (int*)   (ws + (76ull << 20));       // 16 MB
    float*  wt    = (float*) (ws + (92ull << 20));       //  1 MB
    int*    gcnt  = (int*)   (ws + (93ull << 20));       // 512 KB
    double* confp = (double*)(ws + (94ull << 20));       // 32 KB

    hipMemsetAsync(gcnt, 0, (size_t)B_ROWS * NCHUNK * sizeof(int), stream);

    transpose_w<<<512, 256, 0, stream>>>(w, wt);
    prep_keys<<<NKEYS / 256, 256, 0, stream>>>(mk, kbf);
    fuse_q<<<B_ROWS, 256, 0, stream>>>(q, spike, wt, bvec, qn2f, qbf);
    cand_gemm<<<dim3(B_ROWS / 128, NCHUNK), 256, 0, stream>>>(qbf, kbf, cidx, gcnt);
    finalize_rows<<<B_ROWS, 256, 0, stream>>>(cidx, gcnt, qn2f, mk, mv, out, confp);
    conf_reduce<<<1, 256, 0, stream>>>(confp, out);
}

// Round 7
// 1422.268 us; speedup vs baseline: 1.1419x; 1.1419x over previous
//
#include <hip/hip_runtime.h>
#include <stdint.h>
#include <math.h>

typedef unsigned short u16;
typedef __attribute__((ext_vector_type(2))) float floatx2;
typedef __attribute__((ext_vector_type(4))) float floatx4;
typedef __attribute__((ext_vector_type(4))) unsigned int uintx4;
typedef __attribute__((ext_vector_type(8))) __bf16 bf16x8;

#define B_ROWS 4096
#define DK 512
#define NKEYS 65536
#define NCHUNK 32
#define CHUNK (NKEYS / NCHUNK)        // 2048
#define SLOTS 32
#define CAND_PER_ROW (NCHUNK * SLOTS) // 1024
#define THRESH 0.135f

// d_out layout (float32): out[4096*512], conf[1], top_idx[4096*8], attn[4096*8]
#define CONF_OFF 2097152
#define IDX_OFF  2097153
#define ATTN_OFF (IDX_OFF + B_ROWS * 8)

__device__ __forceinline__ u16 f2bf(float x) {
    union { float f; unsigned int u; } v; v.f = x;
    unsigned int r = v.u + 0x7fffu + ((v.u >> 16) & 1u);
    return (u16)(r >> 16);
}

// async global->LDS, 16B per lane; LDS dest is wave-uniform base + lane*16
__device__ __forceinline__ void gload_lds16(const u16* g, u16* l) {
    __builtin_amdgcn_global_load_lds(
        (const __attribute__((address_space(1))) unsigned int*)g,
        (__attribute__((address_space(3))) unsigned int*)l,
        16, 0, 0);
}

// numpy pairwise_sum emulation for sum of squares, n=128 base block:
// r[j] = a[j]^2, then r[j] += a[i+j]^2 for i=8..120, combine as
// ((r0+r1)+(r2+r3))+((r4+r5)+(r6+r7)). Strict f32, no contraction.
__device__ __forceinline__ float np_block128_sq(const float* a) {
#pragma clang fp contract(off)
    float r[8];
    floatx4 p0 = *(const floatx4*)&a[0];
    floatx4 p1 = *(const floatx4*)&a[4];
    r[0] = p0.x * p0.x; r[1] = p0.y * p0.y; r[2] = p0.z * p0.z; r[3] = p0.w * p0.w;
    r[4] = p1.x * p1.x; r[5] = p1.y * p1.y; r[6] = p1.z * p1.z; r[7] = p1.w * p1.w;
    for (int i = 8; i < 128; i += 8) {
        floatx4 q0 = *(const floatx4*)&a[i];
        floatx4 q1 = *(const floatx4*)&a[i + 4];
        r[0] += q0.x * q0.x; r[1] += q0.y * q0.y;
        r[2] += q0.z * q0.z; r[3] += q0.w * q0.w;
        r[4] += q1.x * q1.x; r[5] += q1.y * q1.y;
        r[6] += q1.z * q1.z; r[7] += q1.w * q1.w;
    }
    return ((r[0] + r[1]) + (r[2] + r[3])) + ((r[4] + r[5]) + (r[6] + r[7]));
}

// n=512: numpy recursion: (B0+B1)+(B2+B3)
__device__ __forceinline__ float np_sum512_sq(const float* a) {
#pragma clang fp contract(off)
    float b0 = np_block128_sq(a);
    float b1 = np_block128_sq(a + 128);
    float b2 = np_block128_sq(a + 256);
    float b3 = np_block128_sq(a + 384);
    return (b0 + b1) + (b2 + b3);
}

// correctly-rounded f32 sqrt via f64 (2p+2 rule), immune to compile flags
__device__ __forceinline__ float sqrt_f32_cr(float s) {
    return (float)sqrt((double)s);
}
// correctly-rounded f32 divide via f64 (double-rounding prob ~2^-29)
__device__ __forceinline__ float div_f32_cr(float a, float b) {
    return (float)((double)a / (double)b);
}

// ---------------- P0: W transpose (WT[i][j] = W[j][i]) ----------------
__global__ __launch_bounds__(256) void transpose_w(const float* __restrict__ w,
                                                   float* __restrict__ wt) {
    int j = blockIdx.x, t = threadIdx.x;
    float a = w[(size_t)j * DK + t];
    float b = w[(size_t)j * DK + t + 256];
    wt[(size_t)t * DK + j] = a;
    wt[(size_t)(t + 256) * DK + j] = b;
}

// ---------------- C: emulated-np f32 key normalize ----------------
// one thread per key row; writes keys_n f32 IN PLACE over mem_keys
// (harness restores d_in from pristine before every launch) + bf16 copy.
__global__ __launch_bounds__(256) void prep_keys(float* __restrict__ mk,
                                                 u16* __restrict__ kbf) {
    const int row = blockIdx.x * 256 + threadIdx.x;
    float* kp = mk + (size_t)row * DK;
    float s = np_sum512_sq(kp);
    float nrm = sqrt_f32_cr(s) + 1e-8f;   // norm + eps, both f32 rounded
    for (int i = 0; i < DK; i += 8) {
        floatx4 p0 = *(const floatx4*)&kp[i];
        floatx4 p1 = *(const floatx4*)&kp[i + 4];
        floatx4 n0, n1;
        n0.x = div_f32_cr(p0.x, nrm); n0.y = div_f32_cr(p0.y, nrm);
        n0.z = div_f32_cr(p0.z, nrm); n0.w = div_f32_cr(p0.w, nrm);
        n1.x = div_f32_cr(p1.x, nrm); n1.y = div_f32_cr(p1.y, nrm);
        n1.z = div_f32_cr(p1.z, nrm); n1.w = div_f32_cr(p1.w, nrm);
        union { uintx4 v; u16 u[8]; } pk;
        pk.u[0] = f2bf(n0.x); pk.u[1] = f2bf(n0.y);
        pk.u[2] = f2bf(n0.z); pk.u[3] = f2bf(n0.w);
        pk.u[4] = f2bf(n1.x); pk.u[5] = f2bf(n1.y);
        pk.u[6] = f2bf(n1.z); pk.u[7] = f2bf(n1.w);
        *(floatx4*)&kp[i] = n0;
        *(floatx4*)&kp[i + 4] = n1;
        *(uintx4*)&kbf[(size_t)row * DK + i] = pk.v;
    }
}

// ---------------- AB: emulated-np f32 enc + fused q normalize ----------------
// Unconditional fmaf chain (fmaf(0,w,a)==a bit-exactly since spike values
// are exactly 0.0/1.0 and the accumulator can never be -0), batched 16-deep
// loads so L2 latency pipelines instead of serializing per-iteration, and
// thread->column remap {t,t+256} -> {2t,2t+1} so each row contributes one
// float2 load instead of two scalar loads.
__global__ __launch_bounds__(256) void fuse_q(const float* __restrict__ q,
                                              const float* __restrict__ spike,
                                              const float* __restrict__ wt,
                                              const float* __restrict__ bvec,
                                              float* __restrict__ qn2f,
                                              u16* __restrict__ qbf) {
    __shared__ __align__(16) float s_sp[DK];
    __shared__ __align__(16) float s_q[DK];
    __shared__ __align__(16) float s_y[DK];
    __shared__ float s_nq;
    __shared__ float s_ny;
    const int t = threadIdx.x, b = blockIdx.x;
    s_sp[t] = spike[(size_t)b * DK + t];
    s_sp[t + 256] = spike[(size_t)b * DK + t + 256];
    s_q[t] = q[(size_t)b * DK + t];
    s_q[t + 256] = q[(size_t)b * DK + t + 256];
    __syncthreads();

    const int c0 = 2 * t;   // this thread owns columns c0 and c0+1
    float a0 = 0.f, a1 = 0.f;
    for (int i = 0; i < DK; i += 16) {
        float sv[16]; floatx2 wv[16];
#pragma unroll
        for (int u = 0; u < 16; ++u) {
            sv[u] = s_sp[i + u];
            wv[u] = *(const floatx2*)&wt[(size_t)(i + u) * DK + c0];
        }
#pragma unroll
        for (int u = 0; u < 16; ++u) {
            a0 = fmaf(sv[u], wv[u].x, a0);   // sv==0 contributes exactly nothing
            a1 = fmaf(sv[u], wv[u].y, a1);
        }
    }

    if (t == 0) s_nq = sqrt_f32_cr(np_sum512_sq(s_q)) + 1e-8f;
    __syncthreads();
    float nq = s_nq;
    float qn0 = div_f32_cr(s_q[c0], nq);
    float qn1 = div_f32_cr(s_q[c0 + 1], nq);
    float e0 = a0 + bvec[c0];             // matmul result + b, f32 add
    float e1 = a1 + bvec[c0 + 1];
    float y0, y1;
    {
#pragma clang fp contract(off)
        float u0 = 0.7f * qn0; float v0 = 0.3f * e0; y0 = u0 + v0;
        float u1 = 0.7f * qn1; float v1 = 0.3f * e1; y1 = u1 + v1;
    }
    s_y[c0] = y0; s_y[c0 + 1] = y1;
    __syncthreads();
    if (t == 0) s_ny = sqrt_f32_cr(np_sum512_sq(s_y)) + 1e-8f;
    __syncthreads();
    float ny = s_ny;
    float f0 = div_f32_cr(y0, ny);
    float f1 = div_f32_cr(y1, ny);
    *(floatx2*)&qn2f[(size_t)b * DK + c0] = (floatx2){f0, f1};
    union { unsigned int u; u16 h[2]; } pk;
    pk.h[0] = f2bf(f0); pk.h[1] = f2bf(f1);
    *(unsigned int*)&qbf[(size_t)b * DK + c0] = pk.u;
}

// ---------------- D: bf16 MFMA GEMM + threshold candidate filter ----------------
// T3-minimum 2-phase template (m248): A and B both double-buffered in LDS,
// stage of step s+1 issued BEFORE computing step s, ONE __syncthreads per
// step — the barrier's vmcnt(0) drain lands after 32 MFMA + ds_reads of
// cover instead of immediately after the stage (round-4's stall), and A
// fragments come from LDS (round-6's per-step global A-wait removed).
// XOR swizzle unchanged: linear LDS dest + inverse-swz global source +
// swz ds_read (rule #21). Values bit-identical to the padded-LDS version.
// LDS 64 KB -> 2 blocks/CU; ILP (prefetch depth) replaces TLP.
__global__ __launch_bounds__(256, 2) void cand_gemm(const u16* __restrict__ qbf,
                                                    const u16* __restrict__ kbf,
                                                    int* __restrict__ cidx,
                                                    int* __restrict__ gcnt) {
    __shared__ u16 ldsA[2][128 * 64];
    __shared__ u16 ldsB[2][128 * 64];
    const int t = threadIdx.x;
    const int lane = t & 63;
    const int wave = t >> 6;
    const int qbase = blockIdx.x * 128;
    const int chunk = blockIdx.y;
    const int r0 = 64 * (wave >> 1), c0 = 64 * (wave & 1);
    const int quad = lane >> 4, m16 = lane & 15;

    // staging geometry: wave stages chunks m = wave*4+c (1 KB = 8 rows);
    // lane covers LDS row m*8+(lane>>3), col bytes (lane&7)*16; global col
    // inverse-swizzled: 16*((lane&7) ^ (lane>>3)).
    const int srow = lane >> 3;
    const int scol = ((lane & 7) ^ srow) << 3;     // u16 col offset

    const u16* aB0 = qbf + (size_t)(qbase + wave * 32 + srow) * DK + scol;

    floatx4 acc[4][4];

    // prologue: stage s=0 (iter 0, ks 0) into buf 0
    {
        const u16* bB = kbf + (size_t)(chunk * CHUNK + wave * 32 + srow) * DK + scol;
#pragma unroll
        for (int c = 0; c < 4; ++c) {
            gload_lds16(aB0 + (size_t)c * 8 * DK, &ldsA[0][(wave * 4 + c) * 512]);
            gload_lds16(bB + (size_t)c * 8 * DK, &ldsB[0][(wave * 4 + c) * 512]);
        }
    }
    __syncthreads();

    int cur = 0;
    for (int s = 0; s < 128; ++s) {          // s = iter*8 + kstep
        const int kstep = s & 7;
        const int nbase = chunk * CHUNK + (s >> 3) * 128;

        // stage step s+1 into the other buffer (issued BEFORE compute)
        if (s < 127) {
            const int s2 = s + 1;
            const int ks2 = (s2 & 7) << 6;   // u16 col offset within row
            const u16* aB = aB0 + ks2;
            const u16* bB = kbf + (size_t)(chunk * CHUNK + (s2 >> 3) * 128 +
                                           wave * 32 + srow) * DK + ks2 + scol;
#pragma unroll
            for (int c = 0; c < 4; ++c) {
                gload_lds16(aB + (size_t)c * 8 * DK, &ldsA[cur ^ 1][(wave * 4 + c) * 512]);
                gload_lds16(bB + (size_t)c * 8 * DK, &ldsB[cur ^ 1][(wave * 4 + c) * 512]);
            }
        }

        if (kstep == 0) {
#pragma unroll
            for (int i = 0; i < 4; ++i)
#pragma unroll
                for (int j = 0; j < 4; ++j) acc[i][j] = (floatx4){0.f, 0.f, 0.f, 0.f};
        }

        // compute on buf[cur]
#pragma unroll
        for (int h = 0; h < 2; ++h) {
            const int cb = ((h * 4 + quad) ^ (m16 & 7)) << 4;   // swizzled byte col
            bf16x8 afr[4], bfr[4];
#pragma unroll
            for (int i = 0; i < 4; ++i)
                afr[i] = __builtin_bit_cast(bf16x8,
                    *(const uintx4*)((const char*)&ldsA[cur][0] + (r0 + 16 * i + m16) * 128 + cb));
#pragma unroll
            for (int j = 0; j < 4; ++j)
                bfr[j] = __builtin_bit_cast(bf16x8,
                    *(const uintx4*)((const char*)&ldsB[cur][0] + (c0 + 16 * j + m16) * 128 + cb));
#pragma unroll
            for (int i = 0; i < 4; ++i)
#pragma unroll
                for (int j = 0; j < 4; ++j)
                    acc[i][j] = __builtin_amdgcn_mfma_f32_16x16x32_bf16(
                        afr[h * 0 + i], bfr[j], acc[i][j], 0, 0, 0);
        }

        if (kstep == 7) {
            // C layout: col=lane&15, row=quad*4+reg  [m89/m91-verified]
#pragma unroll
            for (int i = 0; i < 4; ++i)
#pragma unroll
                for (int j = 0; j < 4; ++j) {
                    int col = nbase + c0 + 16 * j + m16;
#pragma unroll
                    for (int r = 0; r < 4; ++r) {
                        float v = acc[i][j][r];
                        if (v > THRESH) {
                            int grow = qbase + r0 + 16 * i + quad * 4 + r;
                            int slot = atomicAdd(&gcnt[grow * NCHUNK + chunk], 1);
                            if (slot < SLOTS)
                                cidx[(size_t)grow * CAND_PER_ROW + chunk * SLOTS + slot] = col;
                        }
                    }
                }
        }
        __syncthreads();   // drains stage(s+1) + orders buf reuse
        cur ^= 1;
    }
}

// ---------------- E: dense rescore (np-f32 emulation) + exact top-8 ----------------
__global__ __launch_bounds__(256) void finalize_rows(const int* __restrict__ cidx,
                                                     const int* __restrict__ gcnt,
                                                     const float* __restrict__ qn2f,
                                                     const float* __restrict__ keys_n,
                                                     const float* __restrict__ mem_values,
                                                     float* __restrict__ out,
                                                     double* __restrict__ confp) {
    __shared__ __align__(16) float s_q[DK];
    __shared__ int s_cnt[NCHUNK];
    __shared__ int s_kin[CAND_PER_ROW];
    __shared__ float s_dv[CAND_PER_ROW];
    __shared__ int s_di[CAND_PER_ROW];
    __shared__ int s_n;
    __shared__ float s_lv[64][8];
    __shared__ int s_li[64][8];
    __shared__ float s_tv[8];
    __shared__ int s_ti[8];
    __shared__ double s_attn[8];

    const int b = blockIdx.x, t = threadIdx.x, lane = t & 63, wave = t >> 6;
    s_q[t] = qn2f[(size_t)b * DK + t];
    s_q[t + 256] = qn2f[(size_t)b * DK + t + 256];
    if (t == 0) s_n = 0;
    if (t < NCHUNK) {
        int c = gcnt[b * NCHUNK + t];
        s_cnt[t] = c < SLOTS ? c : SLOTS;
    }
    __syncthreads();

    // dense compaction of active candidate key-indices
    for (int s = t; s < CAND_PER_ROW; s += 256) {
        int ch = s >> 5, sl = s & 31;
        if (sl < s_cnt[ch]) {
            int pos = atomicAdd(&s_n, 1);
            s_kin[pos] = cidx[(size_t)b * CAND_PER_ROW + s];
        }
    }
    __syncthreads();
    const int n = s_n;

    // rescore: sequential-k single-accumulator fmaf chain over precomputed
    // keys_n (bit-identical to np f32 emulation verified in round 3)
    for (int p = t; p < n; p += 256) {
        int ki = s_kin[p];
        const float* kp = keys_n + (size_t)ki * DK;
        float acc = 0.f;
        for (int i = 0; i < DK; i += 4) {
            floatx4 kv = *(const floatx4*)&kp[i];
            acc = fmaf(s_q[i + 0], kv.x, acc);
            acc = fmaf(s_q[i + 1], kv.y, acc);
            acc = fmaf(s_q[i + 2], kv.z, acc);
            acc = fmaf(s_q[i + 3], kv.w, acc);
        }
        s_dv[p] = acc;
        s_di[p] = ki;
    }
    __syncthreads();

    // stage 1: each lane of wave 0 insertion-sorts its strided entries into
    // top-8 (desc by value; tie -> smaller key index = stable argsort)
    if (wave == 0) {
        float lv[8]; int li[8];
#pragma unroll
        for (int k = 0; k < 8; ++k) { lv[k] = -1e30f; li[k] = 0x7fffffff; }
        for (int p = lane; p < n; p += 64) {
            float v = s_dv[p];
            int ki = s_di[p];
            if (v > lv[7] || (v == lv[7] && ki < li[7])) {
                lv[7] = v; li[7] = ki;
#pragma unroll
                for (int k = 7; k > 0; --k) {
                    bool sw = (lv[k] > lv[k - 1]) ||
                              (lv[k] == lv[k - 1] && li[k] < li[k - 1]);
                    if (sw) {
                        float tv = lv[k]; lv[k] = lv[k - 1]; lv[k - 1] = tv;
                        int ti = li[k]; li[k] = li[k - 1]; li[k - 1] = ti;
                    }
                }
            }
        }
#pragma unroll
        for (int k = 0; k < 8; ++k) { s_lv[lane][k] = lv[k]; s_li[lane][k] = li[k]; }
    }
    __syncthreads();

    // stage 2: single-thread 64-way merge on sorted list heads (exact)
    if (t == 0) {
        int head[64];
#pragma unroll
        for (int l = 0; l < 64; ++l) head[l] = 0;
        for (int k = 0; k < 8; ++k) {
            float bv = -2e30f; int bi = 0x7fffffff; int bl = 0;
            for (int l = 0; l < 64; ++l) {
                int h = head[l];
                float v = s_lv[l][h];
                int ki = s_li[l][h];
                if (v > bv || (v == bv && ki < bi)) { bv = v; bi = ki; bl = l; }
            }
            head[bl]++;
            s_tv[k] = bv;
            s_ti[k] = (bi == 0x7fffffff) ? 0 : bi;
        }
        // softmax + entropy (f64 on the emulated-f32 top values)
        double mx = (double)s_tv[0];
        double e[8], sum = 0.0;
#pragma unroll
        for (int k = 0; k < 8; ++k) {
            e[k] = exp(((double)s_tv[k] - mx) / 0.1);
            sum += e[k];
        }
        double H = 0.0;
#pragma unroll
        for (int k = 0; k < 8; ++k) {
            double pa = e[k] / sum;
            s_attn[k] = pa;
            double pc = pa < 1e-8 ? 1e-8 : pa;
            H -= pc * log(pc);
        }
        confp[b] = 1.0 - H / (log(8.0) + 1e-8);
    }
    __syncthreads();

    if (t < 8) {
        out[IDX_OFF + (size_t)b * 8 + t] = (float)s_ti[t];
        out[ATTN_OFF + (size_t)b * 8 + t] = (float)s_attn[t];
    }
    for (int c = t; c < DK; c += 256) {
        double a = 0.0;
#pragma unroll
        for (int k = 0; k < 8; ++k)
            a += s_attn[k] * (double)mem_values[(size_t)s_ti[k] * DK + c];
        out[(size_t)b * DK + c] = (float)a;
    }
}

// ---------------- F: conf = mean over rows ----------------
__global__ __launch_bounds__(256) void conf_reduce(const double* __restrict__ confp,
                                                   float* __restrict__ out) {
    __shared__ double red[256];
    int t = threadIdx.x;
    double s = 0.0;
    for (int i = t; i < B_ROWS; i += 256) s += confp[i];
    red[t] = s;
    __syncthreads();
    for (int k = 128; k > 0; k >>= 1) {
        if (t < k) red[t] += red[t + k];
        __syncthreads();
    }
    if (t == 0) out[CONF_OFF] = (float)(red[0] / 4096.0);
}

extern "C" void kernel_launch(void* const* d_in, const int* in_sizes, int n_in,
                              void* d_out, int out_size, void* d_ws, size_t ws_size,
                              hipStream_t stream) {
    const float* q     = (const float*)d_in[0];
    const float* spike = (const float*)d_in[1];
    float*       mk    = (float*)d_in[2];   // normalized in place by prep_keys
    const float* mv    = (const float*)d_in[3];
    const float* w     = (const float*)d_in[4];
    const float* bvec  = (const float*)d_in[5];
    float* out = (float*)d_out;
    char* ws = (char*)d_ws;

    // workspace layout (~95 MB)
    u16*    qbf   = (u16*)   (ws);                       //  4 MB
    u16*    kbf   = (u16*)   (ws + (4ull  << 20));       // 64 MB
    float*  qn2f  = (float*) (ws + (68ull << 20));       //  8 MB
    int*    cidx  = (int*)   (ws + (76ull << 20));       // 16 MB
    float*  wt    = (float*) (ws + (92ull << 20));       //  1 MB
    int*    gcnt  = (int*)   (ws + (93ull << 20));       // 512 KB
    double* confp = (double*)(ws + (94ull << 20));       // 32 KB

    hipMemsetAsync(gcnt, 0, (size_t)B_ROWS * NCHUNK * sizeof(int), stream);

    transpose_w<<<512, 256, 0, stream>>>(w, wt);
    prep_keys<<<NKEYS / 256, 256, 0, stream>>>(mk, kbf);
    fuse_q<<<B_ROWS, 256, 0, stream>>>(q, spike, wt, bvec, qn2f, qbf);
    cand_gemm<<<dim3(B_ROWS / 128, NCHUNK), 256, 0, stream>>>(qbf, kbf, cidx, gcnt);
    finalize_rows<<<B_ROWS, 256, 0, stream>>>(cidx, gcnt, qn2f, mk, mv, out, confp);
    conf_reduce<<<1, 256, 0, stream>>>(confp, out);
}